// Round 10
// baseline (192.885 us; speedup 1.0000x reference)
//
#include <hip/hip_runtime.h>

typedef float  floatx4 __attribute__((ext_vector_type(4)));
typedef _Float16 half8 __attribute__((ext_vector_type(8)));
typedef _Float16 half4v __attribute__((ext_vector_type(4)));

__device__ __forceinline__ void gld16(const void* g, void* l) {
    __builtin_amdgcn_global_load_lds(
        (const __attribute__((address_space(1))) void*)g,
        (__attribute__((address_space(3))) void*)l, 16, 0, 0);
}

// ---------------------------------------------------------------- conv x f32->f16
__global__ __launch_bounds__(256) void conv_x_kernel(const float* __restrict__ x,
                                                     _Float16* __restrict__ xh) {
    int i = blockIdx.x * 256 + threadIdx.x;
    float4 v = ((const float4*)x)[i];
    half4v o = { (_Float16)v.x, (_Float16)v.y, (_Float16)v.z, (_Float16)v.w };
    ((half4v*)xh)[i] = o;
}

// ------------------------------------------------- transpose f32 [K][N] -> f16 [N][K]
__global__ __launch_bounds__(256) void transpose_f32f16(const float* __restrict__ W,
                                                        _Float16* __restrict__ WT,
                                                        int K, int N) {
    __shared__ _Float16 t[64][72];
    int n0 = blockIdx.x * 64, k0 = blockIdx.y * 64;
    int c = threadIdx.x & 63, r4 = threadIdx.x >> 6;
    for (int rr = 0; rr < 64; rr += 4) {
        int k = k0 + rr + r4;
        t[rr + r4][c] = (_Float16)W[(size_t)k * N + n0 + c];
    }
    __syncthreads();
    for (int rr = 0; rr < 64; rr += 4) {
        int n = n0 + rr + r4;
        WT[(size_t)n * K + k0 + c] = t[c][rr + r4];
    }
}

// ---------------------------------------------------------------- QKV GEMM + fused RoPE
// 128x128 tile, BK=64, XOR-swizzled LDS. Epilogue: per-wave LDS round-trip; while
// copying out, q/k columns get RoPE applied (t fixed per chunk -> float4 cos/sin
// loads) and land directly in qh/kh [bh][t][hd]; v lands raw in vh (same layout).
__global__ __launch_bounds__(256) void gemm_qkv(const _Float16* __restrict__ A,
                                                const _Float16* __restrict__ BT,
                                                const float* __restrict__ fc,
                                                const float* __restrict__ fs,
                                                _Float16* __restrict__ qh,
                                                _Float16* __restrict__ kh,
                                                _Float16* __restrict__ vh) {
    const int K = 1024, NHALF = 64;
    __shared__ __align__(16) _Float16 sAB[2 * 128 * 64];   // 32 KB
    _Float16* sA = sAB;
    _Float16* sB = sAB + 128 * 64;

    const int tid  = threadIdx.x;
    const int wave = tid >> 6, lane = tid & 63;
    const int lrow = lane & 15, quad = lane >> 4;
    const int bm = blockIdx.x * 128, bn = blockIdx.y * 128;
    const int waveM = (wave >> 1) * 64, waveN = (wave & 1) * 64;

    const int section = bn >> 10;              // 0=q 1=k 2=v (block-uniform)
    const int head_base = (bn & 1023) >> 6;    // 2 heads per 128-col tile
    _Float16* __restrict__ D = (section == 0) ? qh : (section == 1) ? kh : vh;
    const bool dorope = (section < 2);

    floatx4 acc[4][4] = {};

    int srow[4], sccg[4];
#pragma unroll
    for (int hlf = 0; hlf < 4; ++hlf) {
        int s = tid + hlf * 256;
        srow[hlf] = s >> 3;
        sccg[hlf] = ((s & 7) ^ (srow[hlf] & 7)) * 8;
    }

    for (int k0 = 0; k0 < K; k0 += 64) {
#pragma unroll
        for (int hlf = 0; hlf < 4; ++hlf) {
            int s = tid + hlf * 256;
            gld16(A + (size_t)(bm + srow[hlf]) * K + k0 + sccg[hlf], sA + s * 8);
            gld16(BT + (size_t)(bn + srow[hlf]) * K + k0 + sccg[hlf], sB + s * 8);
        }
        __syncthreads();

#pragma unroll
        for (int kk = 0; kk < 2; ++kk) {
            half8 aF[4], bF[4];
#pragma unroll
            for (int mt = 0; mt < 4; ++mt)
                aF[mt] = *(const half8*)&sA[(waveM + mt * 16 + lrow) * 64 +
                                            (((kk * 4 + quad) ^ (lrow & 7)) * 8)];
#pragma unroll
            for (int nt = 0; nt < 4; ++nt)
                bF[nt] = *(const half8*)&sB[(waveN + nt * 16 + lrow) * 64 +
                                            (((kk * 4 + quad) ^ (lrow & 7)) * 8)];
#pragma unroll
            for (int mt = 0; mt < 4; ++mt)
#pragma unroll
                for (int nt = 0; nt < 4; ++nt)
                    acc[mt][nt] = __builtin_amdgcn_mfma_f32_16x16x32_f16(
                        aF[mt], bF[nt], acc[mt][nt], 0, 0, 0);
        }
        __syncthreads();
    }

    // epilogue: per-wave private LDS region, rope on the way out
    _Float16* ep = sAB + wave * 1152;
    const int erow = lane >> 3, ecol = (lane & 7) * 8;
    const int cc = waveN + ecol;               // 0..127 within tile
    const int h = head_base + (cc >> 6), hd = cc & 63, j0 = hd >> 1;
#pragma unroll
    for (int mt = 0; mt < 4; ++mt) {
#pragma unroll
        for (int nt = 0; nt < 4; ++nt)
#pragma unroll
            for (int r = 0; r < 4; ++r)
                ep[(quad * 4 + r) * 72 + nt * 16 + lrow] = (_Float16)acc[mt][nt][r];
        __builtin_amdgcn_wave_barrier();
#pragma unroll
        for (int st = 0; st < 2; ++st) {
            int m = bm + waveM + mt * 16 + st * 8 + erow;
            int b = m >> 11, t = m & 2047;
            half8 v = *(const half8*)&ep[(st * 8 + erow) * 72 + ecol];
            if (dorope) {
                float4 c4 = *(const float4*)&fc[t * 32 + j0];
                float4 s4 = *(const float4*)&fs[t * 32 + j0];
                half8 o;
                float x0, x1;
                x0 = (float)v[0]; x1 = (float)v[1];
                o[0] = (_Float16)(x0 * c4.x - x1 * s4.x);
                o[1] = (_Float16)(x0 * s4.x + x1 * c4.x);
                x0 = (float)v[2]; x1 = (float)v[3];
                o[2] = (_Float16)(x0 * c4.y - x1 * s4.y);
                o[3] = (_Float16)(x0 * s4.y + x1 * c4.y);
                x0 = (float)v[4]; x1 = (float)v[5];
                o[4] = (_Float16)(x0 * c4.z - x1 * s4.z);
                o[5] = (_Float16)(x0 * s4.z + x1 * c4.z);
                x0 = (float)v[6]; x1 = (float)v[7];
                o[6] = (_Float16)(x0 * c4.w - x1 * s4.w);
                o[7] = (_Float16)(x0 * s4.w + x1 * c4.w);
                v = o;
            }
            *(half8*)&D[(((size_t)(b * 16 + h) * 2048 + t) * NHALF) + hd] = v;
        }
        __builtin_amdgcn_wave_barrier();
    }
}

// ---------------------------------------------------------------- GEMM f32 out (proj)
__global__ __launch_bounds__(256) void gemm_tn64(const _Float16* __restrict__ A,
                                                 const _Float16* __restrict__ BT,
                                                 float* __restrict__ C,
                                                 int M, int N, int K) {
    __shared__ __align__(16) _Float16 sA[64 * 32];
    __shared__ __align__(16) _Float16 sB[128 * 32];

    const int tid  = threadIdx.x;
    const int wave = tid >> 6, lane = tid & 63;
    const int lrow = lane & 15, quad = lane >> 4;
    const int bm = blockIdx.x * 64, bn = blockIdx.y * 128;
    const int waveM = (wave >> 1) * 32, waveN = (wave & 1) * 64;

    floatx4 acc[2][4] = {};

    const int raA = tid >> 2, ccA = (((tid & 3) ^ ((tid >> 2) & 3))) * 8;
    int rB[2], cB[2];
#pragma unroll
    for (int hlf = 0; hlf < 2; ++hlf) {
        int s = tid + hlf * 256;
        rB[hlf] = s >> 2;
        cB[hlf] = ((s & 3) ^ ((s >> 2) & 3)) * 8;
    }

    for (int k0 = 0; k0 < K; k0 += 32) {
        gld16(A + (size_t)(bm + raA) * K + k0 + ccA, sA + tid * 8);
#pragma unroll
        for (int hlf = 0; hlf < 2; ++hlf) {
            int s = tid + hlf * 256;
            gld16(BT + (size_t)(bn + rB[hlf]) * K + k0 + cB[hlf], sB + s * 8);
        }
        __syncthreads();

        half8 aF[2], bF[4];
#pragma unroll
        for (int mt = 0; mt < 2; ++mt)
            aF[mt] = *(const half8*)&sA[(waveM + mt * 16 + lrow) * 32 +
                                        ((quad ^ (lrow & 3)) * 8)];
#pragma unroll
        for (int nt = 0; nt < 4; ++nt)
            bF[nt] = *(const half8*)&sB[(waveN + nt * 16 + lrow) * 32 +
                                        ((quad ^ (lrow & 3)) * 8)];
#pragma unroll
        for (int mt = 0; mt < 2; ++mt)
#pragma unroll
            for (int nt = 0; nt < 4; ++nt)
                acc[mt][nt] = __builtin_amdgcn_mfma_f32_16x16x32_f16(
                    aF[mt], bF[nt], acc[mt][nt], 0, 0, 0);
        __syncthreads();
    }

#pragma unroll
    for (int mt = 0; mt < 2; ++mt)
#pragma unroll
        for (int nt = 0; nt < 4; ++nt)
#pragma unroll
            for (int r = 0; r < 4; ++r) {
                int row = bm + waveM + mt * 16 + quad * 4 + r;
                int col = bn + waveN + nt * 16 + lrow;
                C[(size_t)row * N + col] = acc[mt][nt][r];
            }
}

// ---------------------------------------------------------------- V transpose (from compact vh)
// vh [bh][2048][64] -> vt [bh][64][2048]
__global__ __launch_bounds__(256) void vtrans(const _Float16* __restrict__ vh,
                                              _Float16* __restrict__ vt) {
    __shared__ _Float16 s[64][72];
    const int bh = blockIdx.y, t0 = blockIdx.x * 64;
    const int tid = threadIdx.x;
    int c = tid & 63, r4 = tid >> 6;
    const _Float16* src = vh + ((size_t)bh * 2048 + t0) * 64;
    for (int rr = 0; rr < 64; rr += 4)
        s[rr + r4][c] = src[(size_t)(rr + r4) * 64 + c];
    __syncthreads();
    for (int rr = 0; rr < 64; rr += 4)
        vt[((size_t)bh * 64 + rr + r4) * 2048 + t0 + c] = s[c][rr + r4];
}

// ---------------------------------------------------------------- attention, 32 q/wave split-K
#define U_(qc,k0,k1,dir,slot) ((qc)|((k0)<<5)|((k1)<<11)|((dir)<<17)|((slot)<<18))
__device__ const unsigned int UTAB[24] = {
    U_(15, 0,15,0,14), U_(15,16,31,0,15), U_( 7, 0,15,1, 0),
    U_(14, 0,14,0,12), U_(14,15,29,0,13),
    U_(13, 0,13,0,10), U_(13,14,27,0,11), U_( 6, 0,13,1, 0),
    U_(12, 0,12,0, 8), U_(12,13,25,0, 9),
    U_(11, 0,11,0, 6), U_(11,12,23,0, 7), U_( 5, 0,11,1, 0),
    U_(10, 0,10,0, 4), U_(10,11,21,0, 5),
    U_( 9, 0, 9,0, 2), U_( 9,10,19,0, 3), U_( 4, 0, 9,1, 0),
    U_( 8, 0, 8,0, 0), U_( 8, 9,17,0, 1),
    U_( 3, 0, 7,1, 0), U_( 2, 0, 5,1, 0), U_( 1, 0, 3,1, 0), U_( 0, 0, 1,1, 0)
};

__global__ __launch_bounds__(256, 3) void attn_sk2(const _Float16* __restrict__ Q,
                                                   const _Float16* __restrict__ Kk,
                                                   const _Float16* __restrict__ Vt,
                                                   _Float16* __restrict__ Y,
                                                   _Float16* __restrict__ Opart,
                                                   float* __restrict__ lpart) {
    __shared__ __align__(16) _Float16 sK[64 * 64];
    __shared__ __align__(16) _Float16 sV[64 * 64];
    __shared__ __align__(16) _Float16 sP[128 * 72];

    const int bh = blockIdx.x, b = bh >> 4, h = bh & 15;
    const unsigned e = UTAB[blockIdx.y];
    const int qc = e & 31, k0 = (e >> 5) & 63, k1 = (e >> 11) & 63;
    const int dir = (e >> 17) & 1, slot = (e >> 18) & 15;
    const int d0 = 2 * qc, d1 = 2 * qc + 1;

    const int tid = threadIdx.x;
    const int wave = tid >> 6, lane = tid & 63;
    const int lq = lane & 15, quad = lane >> 4;

    const _Float16* Kbase = Kk + (size_t)bh * 2048 * 64;
    const _Float16* Vbase = Vt + (size_t)bh * 64 * 2048;

    const _Float16 qscale = (_Float16)(0.125f * 1.44269504f);
    half8 qF[2][2];
#pragma unroll
    for (int g = 0; g < 2; ++g) {
        const _Float16* Qp = Q + ((size_t)bh * 2048 + qc * 128 + g * 64 + wave * 16 + lq) * 64;
#pragma unroll
        for (int ks = 0; ks < 2; ++ks)
            qF[g][ks] = (*(const half8*)(Qp + ks * 32 + quad * 8)) * qscale;
    }

    floatx4 O0[4] = {}, O1[4] = {};
    float lacc0 = 0.f, lacc1 = 0.f;

    for (int kt = k0; kt <= k1; ++kt) {
        const bool live0 = (kt <= d0);
        const _Float16* kb = Kbase + (size_t)kt * 64 * 64;
        const _Float16* vb = Vbase + kt * 64;
#pragma unroll
        for (int hlf = 0; hlf < 2; ++hlf) {
            int s = tid + hlf * 256;
            int row = s >> 3;
            int ccg = (s & 7) ^ (row & 7);
            gld16(kb + row * 64 + ccg * 8, sK + s * 8);
            gld16(vb + (size_t)row * 2048 + ccg * 8, sV + s * 8);
        }
        __syncthreads();

        half4v P0[4], P1[4];
#pragma unroll
        for (int kt4 = 0; kt4 < 4; ++kt4) {
            half8 kf0 = *(const half8*)&sK[(kt4 * 16 + lq) * 64 + ((quad ^ (lq & 7)) * 8)];
            half8 kf1 = *(const half8*)&sK[(kt4 * 16 + lq) * 64 + (((4 + quad) ^ (lq & 7)) * 8)];
            floatx4 s1 = { -12.f, -12.f, -12.f, -12.f };
            s1 = __builtin_amdgcn_mfma_f32_16x16x32_f16(kf0, qF[1][0], s1, 0, 0, 0);
            s1 = __builtin_amdgcn_mfma_f32_16x16x32_f16(kf1, qF[1][1], s1, 0, 0, 0);
            if (kt == d1) {
#pragma unroll
                for (int r = 0; r < 4; ++r)
                    if (kt4 * 16 + quad * 4 + r > wave * 16 + lq) s1[r] = -1e30f;
            }
#pragma unroll
            for (int r = 0; r < 4; ++r) s1[r] = __builtin_amdgcn_exp2f(s1[r]);
            lacc1 += s1[0] + s1[1] + s1[2] + s1[3];
            P1[kt4] = half4v{ (_Float16)s1[0], (_Float16)s1[1],
                              (_Float16)s1[2], (_Float16)s1[3] };
            if (live0) {
                floatx4 s0 = { -12.f, -12.f, -12.f, -12.f };
                s0 = __builtin_amdgcn_mfma_f32_16x16x32_f16(kf0, qF[0][0], s0, 0, 0, 0);
                s0 = __builtin_amdgcn_mfma_f32_16x16x32_f16(kf1, qF[0][1], s0, 0, 0, 0);
                if (kt == d0) {
#pragma unroll
                    for (int r = 0; r < 4; ++r)
                        if (kt4 * 16 + quad * 4 + r > wave * 16 + lq) s0[r] = -1e30f;
                }
#pragma unroll
                for (int r = 0; r < 4; ++r) s0[r] = __builtin_amdgcn_exp2f(s0[r]);
                lacc0 += s0[0] + s0[1] + s0[2] + s0[3];
                P0[kt4] = half4v{ (_Float16)s0[0], (_Float16)s0[1],
                                  (_Float16)s0[2], (_Float16)s0[3] };
            }
        }

        _Float16* pw1 = &sP[(64 + wave * 16 + lq) * 72];
#pragma unroll
        for (int kt4 = 0; kt4 < 4; ++kt4)
            *(half4v*)(pw1 + kt4 * 16 + quad * 4) = P1[kt4];
        _Float16* pw0 = &sP[(wave * 16 + lq) * 72];
        if (live0) {
#pragma unroll
            for (int kt4 = 0; kt4 < 4; ++kt4)
                *(half4v*)(pw0 + kt4 * 16 + quad * 4) = P0[kt4];
        }
        __builtin_amdgcn_wave_barrier();

        half8 aP0[2], aP1[2];
#pragma unroll
        for (int ks = 0; ks < 2; ++ks) {
            aP1[ks] = *(const half8*)(pw1 + ks * 32 + quad * 8);
            if (live0) aP0[ks] = *(const half8*)(pw0 + ks * 32 + quad * 8);
        }
#pragma unroll
        for (int nt = 0; nt < 4; ++nt)
#pragma unroll
            for (int ks = 0; ks < 2; ++ks) {
                half8 vf = *(const half8*)&sV[(nt * 16 + lq) * 64 +
                                              (((ks * 4 + quad) ^ (lq & 7)) * 8)];
                O1[nt] = __builtin_amdgcn_mfma_f32_16x16x32_f16(aP1[ks], vf, O1[nt], 0, 0, 0);
                if (live0)
                    O0[nt] = __builtin_amdgcn_mfma_f32_16x16x32_f16(aP0[ks], vf, O0[nt], 0, 0, 0);
            }
        __syncthreads();
    }

#pragma unroll
    for (int g = 0; g < 2; ++g) {
        float l = g ? lacc1 : lacc0;
        l += __shfl_xor(l, 16);
        l += __shfl_xor(l, 32);
        floatx4* O = g ? O1 : O0;
        if (dir) {
            float invl = 1.0f / l;
#pragma unroll
            for (int r = 0; r < 4; ++r) {
                float iv = __shfl(invl, (lane & 48) | (quad * 4 + r));
                int q = qc * 128 + g * 64 + wave * 16 + quad * 4 + r;
                size_t rowoff = ((size_t)b * 2048 + q) * 1024 + h * 64;
#pragma unroll
                for (int nt = 0; nt < 4; ++nt)
                    Y[rowoff + nt * 16 + lq] = (_Float16)(O[nt][r] * iv);
            }
        } else {
            int gslot = bh * 16 + slot;
            _Float16* op = Opart + (size_t)gslot * 8192;
#pragma unroll
            for (int r = 0; r < 4; ++r) {
                int row = g * 64 + wave * 16 + quad * 4 + r;
#pragma unroll
                for (int nt = 0; nt < 4; ++nt)
                    op[row * 64 + nt * 16 + lq] = (_Float16)O[nt][r];
            }
            if (quad == 0)
                lpart[gslot * 128 + g * 64 + wave * 16 + lq] = l;
        }
    }
}

// ---------------------------------------------------------------- partial combine + normalize
__global__ __launch_bounds__(256) void attn_reduce2(const _Float16* __restrict__ Opart,
                                                    const float* __restrict__ lpart,
                                                    _Float16* __restrict__ Y) {
    const int bh = blockIdx.x, b = bh >> 4, h = bh & 15;
    const int qcx = blockIdx.y, qc = 8 + qcx;
    const int g0 = bh * 16 + qcx * 2, g1 = g0 + 1;
    const int tid = threadIdx.x;

#pragma unroll
    for (int it = 0; it < 2; ++it) {
        int idx = tid + it * 256;
        int row = idx >> 2, cs = (idx & 3) * 16;
        const _Float16* p0 = Opart + (size_t)g0 * 8192 + row * 64 + cs;
        const _Float16* p1 = Opart + (size_t)g1 * 8192 + row * 64 + cs;
        float invl = 1.0f / (lpart[g0 * 128 + row] + lpart[g1 * 128 + row]);
        half8 a0 = *(const half8*)p0, a1 = *(const half8*)(p0 + 8);
        half8 b0 = *(const half8*)p1, b1 = *(const half8*)(p1 + 8);
        half8 o0, o1;
#pragma unroll
        for (int i = 0; i < 8; ++i) {
            o0[i] = (_Float16)(((float)a0[i] + (float)b0[i]) * invl);
            o1[i] = (_Float16)(((float)a1[i] + (float)b1[i]) * invl);
        }
        _Float16* y = Y + ((size_t)b * 2048 + qc * 128 + row) * 1024 + h * 64 + cs;
        *(half8*)y = o0;
        *(half8*)(y + 8) = o1;
    }
}

// ---------------------------------------------------------------- launch
extern "C" void kernel_launch(void* const* d_in, const int* in_sizes, int n_in,
                              void* d_out, int out_size, void* d_ws, size_t ws_size,
                              hipStream_t stream) {
    const float* x     = (const float*)d_in[0];
    const float* wqkv  = (const float*)d_in[1];
    const float* wproj = (const float*)d_in[2];
    const float* fc    = (const float*)d_in[3];
    const float* fs    = (const float*)d_in[4];
    float* out = (float*)d_out;

    char* ws = (char*)d_ws;
    _Float16* xh    = (_Float16*)(ws);                       // 8 MB  (reused as yh)
    _Float16* wqT   = (_Float16*)(ws + ((size_t)8  << 20));  // 6 MB
    _Float16* wpT   = (_Float16*)(ws + ((size_t)14 << 20));  // 2 MB
    _Float16* vh    = (_Float16*)(ws + ((size_t)16 << 20));  // 8 MB (compact v)
    _Float16* Opart = (_Float16*)(ws + ((size_t)24 << 20));  // 8 MB
    float*    lpartf= (float*)(ws + ((size_t)33 << 20));     // 256 KB
    _Float16* qh    = (_Float16*)(ws + ((size_t)40 << 20));  // 8 MB
    _Float16* kh    = (_Float16*)(ws + ((size_t)48 << 20));  // 8 MB
    _Float16* vt    = (_Float16*)(ws + ((size_t)56 << 20));  // 8 MB
    _Float16* yh    = xh;                                    // x dead after gemm_qkv

    conv_x_kernel<<<4096, 256, 0, stream>>>(x, xh);
    transpose_f32f16<<<dim3(48, 16), 256, 0, stream>>>(wqkv, wqT, 1024, 3072);
    transpose_f32f16<<<dim3(16, 16), 256, 0, stream>>>(wproj, wpT, 1024, 1024);
    gemm_qkv<<<dim3(32, 24), 256, 0, stream>>>(xh, wqT, fc, fs, qh, kh, vh);
    vtrans<<<dim3(32, 32), 256, 0, stream>>>(vh, vt);
    attn_sk2<<<dim3(32, 24), 256, 0, stream>>>(qh, kh, vt, yh, Opart, lpartf);
    attn_reduce2<<<dim3(32, 8), 256, 0, stream>>>(Opart, lpartf, yh);
    gemm_tn64<<<dim3(64, 8), 256, 0, stream>>>(yh, wpT, out, 4096, 1024, 1024);
}

// Round 11
// 186.336 us; speedup vs baseline: 1.0351x; 1.0351x over previous
//
#include <hip/hip_runtime.h>

typedef float  floatx4 __attribute__((ext_vector_type(4)));
typedef _Float16 half8 __attribute__((ext_vector_type(8)));
typedef _Float16 half4v __attribute__((ext_vector_type(4)));

__device__ __forceinline__ void gld16(const void* g, void* l) {
    __builtin_amdgcn_global_load_lds(
        (const __attribute__((address_space(1))) void*)g,
        (__attribute__((address_space(3))) void*)l, 16, 0, 0);
}

// ---------------------------------------------------------------- prep: conv x + both W transposes
// blocks [0,4096): x f32->f16 ; [4096,4864): wqkv [K][N]->[N][K] f16 ; [4864,5120): wproj
__global__ __launch_bounds__(256) void prep(const float* __restrict__ x,
                                            const float* __restrict__ wqkv,
                                            const float* __restrict__ wproj,
                                            _Float16* __restrict__ xh,
                                            _Float16* __restrict__ wqT,
                                            _Float16* __restrict__ wpT) {
    __shared__ _Float16 t[64][72];
    const int bid = blockIdx.x, tid = threadIdx.x;
    if (bid < 4096) {
        int i = bid * 256 + tid;
        float4 v = ((const float4*)x)[i];
        half4v o = { (_Float16)v.x, (_Float16)v.y, (_Float16)v.z, (_Float16)v.w };
        ((half4v*)xh)[i] = o;
        return;
    }
    const float* W; _Float16* WT; int K, N, n0, k0;
    if (bid < 4096 + 768) {
        int q = bid - 4096; W = wqkv; WT = wqT; K = 1024; N = 3072;
        n0 = (q % 48) * 64; k0 = (q / 48) * 64;
    } else {
        int q = bid - 4864; W = wproj; WT = wpT; K = 1024; N = 1024;
        n0 = (q % 16) * 64; k0 = (q / 16) * 64;
    }
    int c = tid & 63, r4 = tid >> 6;
    for (int rr = 0; rr < 64; rr += 4)
        t[rr + r4][c] = (_Float16)W[(size_t)(k0 + rr + r4) * N + n0 + c];
    __syncthreads();
    for (int rr = 0; rr < 64; rr += 4)
        WT[(size_t)(n0 + rr + r4) * K + k0 + c] = t[c][rr + r4];
}

// ---------------------------------------------------------------- QKV GEMM (f16 out)
// 128x128 tile, BK=64, XOR-swizzled LDS, 8 waves (wave-tile 64x32) -> 24 waves/CU.
__global__ __launch_bounds__(512) void gemm_tn(const _Float16* __restrict__ A,
                                               const _Float16* __restrict__ BT,
                                               _Float16* __restrict__ Cf16,
                                               int M, int N, int K) {
    __shared__ __align__(16) _Float16 sAB[2 * 128 * 64];   // 32 KB
    _Float16* sA = sAB;
    _Float16* sB = sAB + 128 * 64;

    const int tid  = threadIdx.x;
    const int wave = tid >> 6, lane = tid & 63;
    const int lrow = lane & 15, quad = lane >> 4;
    const int bm = blockIdx.x * 128, bn = blockIdx.y * 128;
    const int waveM = (wave >> 2) * 64, waveN = (wave & 3) * 32;

    floatx4 acc[4][2] = {};

    int srow[2], sccg[2];
#pragma unroll
    for (int hlf = 0; hlf < 2; ++hlf) {
        int s = tid + hlf * 512;
        srow[hlf] = s >> 3;
        sccg[hlf] = ((s & 7) ^ (srow[hlf] & 7)) * 8;
    }

    for (int k0 = 0; k0 < K; k0 += 64) {
#pragma unroll
        for (int hlf = 0; hlf < 2; ++hlf) {
            int s = tid + hlf * 512;
            gld16(A + (size_t)(bm + srow[hlf]) * K + k0 + sccg[hlf], sA + s * 8);
            gld16(BT + (size_t)(bn + srow[hlf]) * K + k0 + sccg[hlf], sB + s * 8);
        }
        __syncthreads();

#pragma unroll
        for (int kk = 0; kk < 2; ++kk) {
            half8 aF[4], bF[2];
#pragma unroll
            for (int mt = 0; mt < 4; ++mt)
                aF[mt] = *(const half8*)&sA[(waveM + mt * 16 + lrow) * 64 +
                                            (((kk * 4 + quad) ^ (lrow & 7)) * 8)];
#pragma unroll
            for (int nt = 0; nt < 2; ++nt)
                bF[nt] = *(const half8*)&sB[(waveN + nt * 16 + lrow) * 64 +
                                            (((kk * 4 + quad) ^ (lrow & 7)) * 8)];
#pragma unroll
            for (int mt = 0; mt < 4; ++mt)
#pragma unroll
                for (int nt = 0; nt < 2; ++nt)
                    acc[mt][nt] = __builtin_amdgcn_mfma_f32_16x16x32_f16(
                        aF[mt], bF[nt], acc[mt][nt], 0, 0, 0);
        }
        __syncthreads();
    }

    // barrier-free f16 epilogue: per-wave private 16x36 region, 4 passes
    _Float16* ep = sAB + wave * 576;
    const int erow = lane >> 2, ecol = (lane & 3) * 8;
#pragma unroll
    for (int mt = 0; mt < 4; ++mt) {
#pragma unroll
        for (int nt = 0; nt < 2; ++nt)
#pragma unroll
            for (int r = 0; r < 4; ++r)
                ep[(quad * 4 + r) * 36 + nt * 16 + lrow] = (_Float16)acc[mt][nt][r];
        __builtin_amdgcn_wave_barrier();
        {
            uint4 d = *(const uint4*)&ep[erow * 36 + ecol];
            *(uint4*)&Cf16[(size_t)(bm + waveM + mt * 16 + erow) * N +
                           bn + waveN + ecol] = d;
        }
        __builtin_amdgcn_wave_barrier();
    }
}

// ---------------------------------------------------------------- proj GEMM (f32 out)
// 64x128 tile, BK=32, XOR-swizzled, 8 waves (wave-tile 32x32) -> 16 waves/CU.
__global__ __launch_bounds__(512) void gemm_tn64(const _Float16* __restrict__ A,
                                                 const _Float16* __restrict__ BT,
                                                 float* __restrict__ C,
                                                 int M, int N, int K) {
    __shared__ __align__(16) _Float16 sA[64 * 32];
    __shared__ __align__(16) _Float16 sB[128 * 32];

    const int tid  = threadIdx.x;
    const int wave = tid >> 6, lane = tid & 63;
    const int lrow = lane & 15, quad = lane >> 4;
    const int bm = blockIdx.x * 64, bn = blockIdx.y * 128;
    const int waveM = (wave >> 2) * 32, waveN = (wave & 3) * 32;

    floatx4 acc[2][2] = {};

    const int rA = tid >> 2, cA = (((tid & 3) ^ ((tid >> 2) & 3))) * 8;   // tid<256 only
    const int rB = tid >> 2, cB = (((tid & 3) ^ ((tid >> 2) & 3))) * 8;

    for (int k0 = 0; k0 < K; k0 += 32) {
        if (tid < 256)
            gld16(A + (size_t)(bm + rA) * K + k0 + cA, sA + tid * 8);
        gld16(BT + (size_t)(bn + rB) * K + k0 + cB, sB + tid * 8);
        __syncthreads();

        half8 aF[2], bF[2];
#pragma unroll
        for (int mt = 0; mt < 2; ++mt)
            aF[mt] = *(const half8*)&sA[(waveM + mt * 16 + lrow) * 32 +
                                        ((quad ^ (lrow & 3)) * 8)];
#pragma unroll
        for (int nt = 0; nt < 2; ++nt)
            bF[nt] = *(const half8*)&sB[(waveN + nt * 16 + lrow) * 32 +
                                        ((quad ^ (lrow & 3)) * 8)];
#pragma unroll
        for (int mt = 0; mt < 2; ++mt)
#pragma unroll
            for (int nt = 0; nt < 2; ++nt)
                acc[mt][nt] = __builtin_amdgcn_mfma_f32_16x16x32_f16(
                    aF[mt], bF[nt], acc[mt][nt], 0, 0, 0);
        __syncthreads();
    }

#pragma unroll
    for (int mt = 0; mt < 2; ++mt)
#pragma unroll
        for (int nt = 0; nt < 2; ++nt)
#pragma unroll
            for (int r = 0; r < 4; ++r) {
                int row = bm + waveM + mt * 16 + quad * 4 + r;
                int col = bn + waveN + nt * 16 + lrow;
                C[(size_t)row * N + col] = acc[mt][nt][r];
            }
}

// ---------------------------------------------------------------- fused RoPE(q,k) + V transpose
__global__ __launch_bounds__(256) void rope_vt(const _Float16* __restrict__ qkv,
                                               const float* __restrict__ fc,
                                               const float* __restrict__ fs,
                                               _Float16* __restrict__ qh,
                                               _Float16* __restrict__ kh,
                                               _Float16* __restrict__ vt) {
    __shared__ _Float16 s[64][72];
    const int bh = blockIdx.y, b = bh >> 4, h = bh & 15;
    const int t0 = blockIdx.x * 64;
    const int tid = threadIdx.x;

    {
        int c4 = (tid & 15) * 4;
        int j0 = c4 >> 1;
        int rr = tid >> 4;
#pragma unroll
        for (int pass = 0; pass < 4; ++pass) {
            int tt = t0 + pass * 16 + rr;
            const _Float16* src = qkv + (size_t)(b * 2048 + tt) * 3072 + h * 64 + c4;
            float c0 = fc[tt * 32 + j0],     s0 = fs[tt * 32 + j0];
            float c1 = fc[tt * 32 + j0 + 1], s1 = fs[tt * 32 + j0 + 1];
            half4v qv = *(const half4v*)(src);
            half4v kv = *(const half4v*)(src + 1024);
            half4v qo, ko;
            {
                float x0 = (float)qv[0], x1 = (float)qv[1];
                qo[0] = (_Float16)(x0 * c0 - x1 * s0); qo[1] = (_Float16)(x0 * s0 + x1 * c0);
                x0 = (float)qv[2]; x1 = (float)qv[3];
                qo[2] = (_Float16)(x0 * c1 - x1 * s1); qo[3] = (_Float16)(x0 * s1 + x1 * c1);
                x0 = (float)kv[0]; x1 = (float)kv[1];
                ko[0] = (_Float16)(x0 * c0 - x1 * s0); ko[1] = (_Float16)(x0 * s0 + x1 * c0);
                x0 = (float)kv[2]; x1 = (float)kv[3];
                ko[2] = (_Float16)(x0 * c1 - x1 * s1); ko[3] = (_Float16)(x0 * s1 + x1 * c1);
            }
            size_t o = ((size_t)bh * 2048 + tt) * 64 + c4;
            *(half4v*)&qh[o] = qo;
            *(half4v*)&kh[o] = ko;
        }
    }
    {
        int c = tid & 63, r4 = tid >> 6;
        const _Float16* srcv = qkv + 2048 + h * 64;
        for (int rr = 0; rr < 64; rr += 4)
            s[rr + r4][c] = srcv[(size_t)(b * 2048 + t0 + rr + r4) * 3072 + c];
        __syncthreads();
        for (int rr = 0; rr < 64; rr += 4)
            vt[((size_t)bh * 64 + rr + r4) * 2048 + t0 + c] = s[c][rr + r4];
    }
}

// ---------------------------------------------------------------- attention, 32 q/wave split-K
#define U_(qc,k0,k1,dir,slot) ((qc)|((k0)<<5)|((k1)<<11)|((dir)<<17)|((slot)<<18))
__device__ const unsigned int UTAB[24] = {
    U_(15, 0,15,0,14), U_(15,16,31,0,15), U_( 7, 0,15,1, 0),
    U_(14, 0,14,0,12), U_(14,15,29,0,13),
    U_(13, 0,13,0,10), U_(13,14,27,0,11), U_( 6, 0,13,1, 0),
    U_(12, 0,12,0, 8), U_(12,13,25,0, 9),
    U_(11, 0,11,0, 6), U_(11,12,23,0, 7), U_( 5, 0,11,1, 0),
    U_(10, 0,10,0, 4), U_(10,11,21,0, 5),
    U_( 9, 0, 9,0, 2), U_( 9,10,19,0, 3), U_( 4, 0, 9,1, 0),
    U_( 8, 0, 8,0, 0), U_( 8, 9,17,0, 1),
    U_( 3, 0, 7,1, 0), U_( 2, 0, 5,1, 0), U_( 1, 0, 3,1, 0), U_( 0, 0, 1,1, 0)
};

__global__ __launch_bounds__(256, 3) void attn_sk2(const _Float16* __restrict__ Q,
                                                   const _Float16* __restrict__ Kk,
                                                   const _Float16* __restrict__ Vt,
                                                   _Float16* __restrict__ Y,
                                                   _Float16* __restrict__ Opart,
                                                   float* __restrict__ lpart) {
    __shared__ __align__(16) _Float16 sK[64 * 64];
    __shared__ __align__(16) _Float16 sV[64 * 64];
    __shared__ __align__(16) _Float16 sP[128 * 72];

    const int bh = blockIdx.x, b = bh >> 4, h = bh & 15;
    const unsigned e = UTAB[blockIdx.y];
    const int qc = e & 31, k0 = (e >> 5) & 63, k1 = (e >> 11) & 63;
    const int dir = (e >> 17) & 1, slot = (e >> 18) & 15;
    const int d0 = 2 * qc, d1 = 2 * qc + 1;

    const int tid = threadIdx.x;
    const int wave = tid >> 6, lane = tid & 63;
    const int lq = lane & 15, quad = lane >> 4;

    const _Float16* Kbase = Kk + (size_t)bh * 2048 * 64;
    const _Float16* Vbase = Vt + (size_t)bh * 64 * 2048;

    const _Float16 qscale = (_Float16)(0.125f * 1.44269504f);
    half8 qF[2][2];
#pragma unroll
    for (int g = 0; g < 2; ++g) {
        const _Float16* Qp = Q + ((size_t)bh * 2048 + qc * 128 + g * 64 + wave * 16 + lq) * 64;
#pragma unroll
        for (int ks = 0; ks < 2; ++ks)
            qF[g][ks] = (*(const half8*)(Qp + ks * 32 + quad * 8)) * qscale;
    }

    floatx4 O0[4] = {}, O1[4] = {};
    float lacc0 = 0.f, lacc1 = 0.f;

    for (int kt = k0; kt <= k1; ++kt) {
        const bool live0 = (kt <= d0);
        const _Float16* kb = Kbase + (size_t)kt * 64 * 64;
        const _Float16* vb = Vbase + kt * 64;
#pragma unroll
        for (int hlf = 0; hlf < 2; ++hlf) {
            int s = tid + hlf * 256;
            int row = s >> 3;
            int ccg = (s & 7) ^ (row & 7);
            gld16(kb + row * 64 + ccg * 8, sK + s * 8);
            gld16(vb + (size_t)row * 2048 + ccg * 8, sV + s * 8);
        }
        __syncthreads();

        half4v P0[4], P1[4];
#pragma unroll
        for (int kt4 = 0; kt4 < 4; ++kt4) {
            half8 kf0 = *(const half8*)&sK[(kt4 * 16 + lq) * 64 + ((quad ^ (lq & 7)) * 8)];
            half8 kf1 = *(const half8*)&sK[(kt4 * 16 + lq) * 64 + (((4 + quad) ^ (lq & 7)) * 8)];
            floatx4 s1 = { -12.f, -12.f, -12.f, -12.f };
            s1 = __builtin_amdgcn_mfma_f32_16x16x32_f16(kf0, qF[1][0], s1, 0, 0, 0);
            s1 = __builtin_amdgcn_mfma_f32_16x16x32_f16(kf1, qF[1][1], s1, 0, 0, 0);
            if (kt == d1) {
#pragma unroll
                for (int r = 0; r < 4; ++r)
                    if (kt4 * 16 + quad * 4 + r > wave * 16 + lq) s1[r] = -1e30f;
            }
#pragma unroll
            for (int r = 0; r < 4; ++r) s1[r] = __builtin_amdgcn_exp2f(s1[r]);
            lacc1 += s1[0] + s1[1] + s1[2] + s1[3];
            P1[kt4] = half4v{ (_Float16)s1[0], (_Float16)s1[1],
                              (_Float16)s1[2], (_Float16)s1[3] };
            if (live0) {
                floatx4 s0 = { -12.f, -12.f, -12.f, -12.f };
                s0 = __builtin_amdgcn_mfma_f32_16x16x32_f16(kf0, qF[0][0], s0, 0, 0, 0);
                s0 = __builtin_amdgcn_mfma_f32_16x16x32_f16(kf1, qF[0][1], s0, 0, 0, 0);
                if (kt == d0) {
#pragma unroll
                    for (int r = 0; r < 4; ++r)
                        if (kt4 * 16 + quad * 4 + r > wave * 16 + lq) s0[r] = -1e30f;
                }
#pragma unroll
                for (int r = 0; r < 4; ++r) s0[r] = __builtin_amdgcn_exp2f(s0[r]);
                lacc0 += s0[0] + s0[1] + s0[2] + s0[3];
                P0[kt4] = half4v{ (_Float16)s0[0], (_Float16)s0[1],
                                  (_Float16)s0[2], (_Float16)s0[3] };
            }
        }

        _Float16* pw1 = &sP[(64 + wave * 16 + lq) * 72];
#pragma unroll
        for (int kt4 = 0; kt4 < 4; ++kt4)
            *(half4v*)(pw1 + kt4 * 16 + quad * 4) = P1[kt4];
        _Float16* pw0 = &sP[(wave * 16 + lq) * 72];
        if (live0) {
#pragma unroll
            for (int kt4 = 0; kt4 < 4; ++kt4)
                *(half4v*)(pw0 + kt4 * 16 + quad * 4) = P0[kt4];
        }
        __builtin_amdgcn_wave_barrier();

        half8 aP0[2], aP1[2];
#pragma unroll
        for (int ks = 0; ks < 2; ++ks) {
            aP1[ks] = *(const half8*)(pw1 + ks * 32 + quad * 8);
            if (live0) aP0[ks] = *(const half8*)(pw0 + ks * 32 + quad * 8);
        }
#pragma unroll
        for (int nt = 0; nt < 4; ++nt)
#pragma unroll
            for (int ks = 0; ks < 2; ++ks) {
                half8 vf = *(const half8*)&sV[(nt * 16 + lq) * 64 +
                                              (((ks * 4 + quad) ^ (lq & 7)) * 8)];
                O1[nt] = __builtin_amdgcn_mfma_f32_16x16x32_f16(aP1[ks], vf, O1[nt], 0, 0, 0);
                if (live0)
                    O0[nt] = __builtin_amdgcn_mfma_f32_16x16x32_f16(aP0[ks], vf, O0[nt], 0, 0, 0);
            }
        __syncthreads();
    }

#pragma unroll
    for (int g = 0; g < 2; ++g) {
        float l = g ? lacc1 : lacc0;
        l += __shfl_xor(l, 16);
        l += __shfl_xor(l, 32);
        floatx4* O = g ? O1 : O0;
        if (dir) {
            float invl = 1.0f / l;
#pragma unroll
            for (int r = 0; r < 4; ++r) {
                float iv = __shfl(invl, (lane & 48) | (quad * 4 + r));
                int q = qc * 128 + g * 64 + wave * 16 + quad * 4 + r;
                size_t rowoff = ((size_t)b * 2048 + q) * 1024 + h * 64;
#pragma unroll
                for (int nt = 0; nt < 4; ++nt)
                    Y[rowoff + nt * 16 + lq] = (_Float16)(O[nt][r] * iv);
            }
        } else {
            int gslot = bh * 16 + slot;
            _Float16* op = Opart + (size_t)gslot * 8192;
#pragma unroll
            for (int r = 0; r < 4; ++r) {
                int row = g * 64 + wave * 16 + quad * 4 + r;
#pragma unroll
                for (int nt = 0; nt < 4; ++nt)
                    op[row * 64 + nt * 16 + lq] = (_Float16)O[nt][r];
            }
            if (quad == 0)
                lpart[gslot * 128 + g * 64 + wave * 16 + lq] = l;
        }
    }
}

// ---------------------------------------------------------------- partial combine + normalize
__global__ __launch_bounds__(256) void attn_reduce2(const _Float16* __restrict__ Opart,
                                                    const float* __restrict__ lpart,
                                                    _Float16* __restrict__ Y) {
    const int bh = blockIdx.x, b = bh >> 4, h = bh & 15;
    const int qcx = blockIdx.y, qc = 8 + qcx;
    const int g0 = bh * 16 + qcx * 2, g1 = g0 + 1;
    const int tid = threadIdx.x;

#pragma unroll
    for (int it = 0; it < 2; ++it) {
        int idx = tid + it * 256;
        int row = idx >> 2, cs = (idx & 3) * 16;
        const _Float16* p0 = Opart + (size_t)g0 * 8192 + row * 64 + cs;
        const _Float16* p1 = Opart + (size_t)g1 * 8192 + row * 64 + cs;
        float invl = 1.0f / (lpart[g0 * 128 + row] + lpart[g1 * 128 + row]);
        half8 a0 = *(const half8*)p0, a1 = *(const half8*)(p0 + 8);
        half8 b0 = *(const half8*)p1, b1 = *(const half8*)(p1 + 8);
        half8 o0, o1;
#pragma unroll
        for (int i = 0; i < 8; ++i) {
            o0[i] = (_Float16)(((float)a0[i] + (float)b0[i]) * invl);
            o1[i] = (_Float16)(((float)a1[i] + (float)b1[i]) * invl);
        }
        _Float16* y = Y + ((size_t)b * 2048 + qc * 128 + row) * 1024 + h * 64 + cs;
        *(half8*)y = o0;
        *(half8*)(y + 8) = o1;
    }
}

// ---------------------------------------------------------------- launch
extern "C" void kernel_launch(void* const* d_in, const int* in_sizes, int n_in,
                              void* d_out, int out_size, void* d_ws, size_t ws_size,
                              hipStream_t stream) {
    const float* x     = (const float*)d_in[0];
    const float* wqkv  = (const float*)d_in[1];
    const float* wproj = (const float*)d_in[2];
    const float* fc    = (const float*)d_in[3];
    const float* fs    = (const float*)d_in[4];
    float* out = (float*)d_out;

    char* ws = (char*)d_ws;
    _Float16* xh    = (_Float16*)(ws);                       // 8 MB  (reused as yh)
    _Float16* wqT   = (_Float16*)(ws + ((size_t)8  << 20));  // 6 MB
    _Float16* wpT   = (_Float16*)(ws + ((size_t)14 << 20));  // 2 MB
    _Float16* qkvh  = (_Float16*)(ws + ((size_t)16 << 20));  // 24 MB (dead after rope_vt)
    _Float16* qh    = (_Float16*)(ws + ((size_t)40 << 20));  // 8 MB
    _Float16* kh    = (_Float16*)(ws + ((size_t)48 << 20));  // 8 MB
    _Float16* vt    = (_Float16*)(ws + ((size_t)56 << 20));  // 8 MB
    _Float16* yh    = xh;                                    // x dead after gemm_tn
    _Float16* Opart = qkvh;                                  // 8 MB, reuses dead qkvh
    float*    lpartf= (float*)(ws + ((size_t)26 << 20));     // 256 KB, inside dead qkvh

    prep<<<5120, 256, 0, stream>>>(x, wqkv, wproj, xh, wqT, wpT);
    gemm_tn<<<dim3(32, 24), 512, 0, stream>>>(xh, wqT, qkvh, 4096, 3072, 1024);
    rope_vt<<<dim3(32, 32), 256, 0, stream>>>(qkvh, fc, fs, qh, kh, vt);
    attn_sk2<<<dim3(32, 24), 256, 0, stream>>>(qh, kh, vt, yh, Opart, lpartf);
    attn_reduce2<<<dim3(32, 8), 256, 0, stream>>>(Opart, lpartf, yh);
    gemm_tn64<<<dim3(64, 8), 512, 0, stream>>>(yh, wpT, out, 4096, 1024, 1024);
}